// Round 3
// baseline (528.029 us; speedup 1.0000x reference)
//
#include <hip/hip_runtime.h>
#include <hip/hip_bf16.h>

// Output: (1, 8, 4096, 4096) float32, 512 MiB per call -> write-BW bound.
//   c in [0,4):  out[c,i,j] = table[seq[i]*4 + c]      (constant along j)
//   c in [4,8):  out[c,i,j] = table[seq[j]*4 + (c-4)]  (same row repeated for all i)
//
// 8192 blocks x 256 threads; each block fills 4 rows (64 KB) of one plane.
// 16 independent 16B NT stores per thread (high MLP); table lookups done via
// cndmask-selects from 4 registers instead of per-lane gathers.

#define L 4096

typedef float v4f __attribute__((ext_vector_type(4)));
typedef int   v4i __attribute__((ext_vector_type(4)));

__global__ __launch_bounds__(256) void SequenceEmbedding_30923764532139_kernel(
        const int* __restrict__ seq,
        const float* __restrict__ table,
        float* __restrict__ out) {
    unsigned b = blockIdx.x;
    unsigned t = threadIdx.x;
    unsigned c = b >> 10;            // plane 0..7 (block-uniform)
    unsigned g = b & 1023u;          // row-group: rows 4g .. 4g+3
    unsigned i0 = g << 2;
    unsigned cc = c & 3u;            // table column for this plane

    // table column cc, one value per base id (seq values are 0..3)
    float t0 = table[0u * 4u + cc];
    float t1 = table[1u * 4u + cc];
    float t2 = table[2u * 4u + cc];
    float t3 = table[3u * 4u + cc];

    size_t plane = (size_t)c << 24;  // c * L * L elements
    v4f* outv = (v4f*)out;

    if (c < 4u) {
        // Row value constant along j; 4 rows, 4 chunks each.
        #pragma unroll
        for (int r = 0; r < 4; ++r) {
            unsigned i = i0 + (unsigned)r;
            int s = seq[i];                       // wave-broadcast load
            float x = s == 0 ? t0 : s == 1 ? t1 : s == 2 ? t2 : t3;
            v4f val = {x, x, x, x};
            size_t base = (plane + (size_t)i * L) >> 2;   // v4f index
            #pragma unroll
            for (int k = 0; k < 4; ++k)
                __builtin_nontemporal_store(val, outv + base + t + 256u * (unsigned)k);
        }
    } else {
        // Row content identical for every i: compute the 4 chunks once, store x4 rows.
        v4f vals[4];
        #pragma unroll
        for (int k = 0; k < 4; ++k) {
            unsigned jf4 = t + 256u * (unsigned)k;        // float4 index within row
            v4i s = *(const v4i*)(seq + 4u * jf4);        // coalesced 16B load
            v4f v;
            v.x = s.x == 0 ? t0 : s.x == 1 ? t1 : s.x == 2 ? t2 : t3;
            v.y = s.y == 0 ? t0 : s.y == 1 ? t1 : s.y == 2 ? t2 : t3;
            v.z = s.z == 0 ? t0 : s.z == 1 ? t1 : s.z == 2 ? t2 : t3;
            v.w = s.w == 0 ? t0 : s.w == 1 ? t1 : s.w == 2 ? t2 : t3;
            vals[k] = v;
        }
        #pragma unroll
        for (int r = 0; r < 4; ++r) {
            size_t base = (plane + (size_t)(i0 + (unsigned)r) * L) >> 2;
            #pragma unroll
            for (int k = 0; k < 4; ++k)
                __builtin_nontemporal_store(vals[k], outv + base + t + 256u * (unsigned)k);
        }
    }
}

extern "C" void kernel_launch(void* const* d_in, const int* in_sizes, int n_in,
                              void* d_out, int out_size, void* d_ws, size_t ws_size,
                              hipStream_t stream) {
    const int*   seq   = (const int*)d_in[0];
    const float* table = (const float*)d_in[1];
    float*       out   = (float*)d_out;

    dim3 block(256);
    dim3 grid(8192);   // 8 planes x 1024 row-groups; 64 KB per block
    SequenceEmbedding_30923764532139_kernel<<<grid, block, 0, stream>>>(seq, table, out);
}

// Round 4
// 523.381 us; speedup vs baseline: 1.0089x; 1.0089x over previous
//
#include <hip/hip_runtime.h>
#include <hip/hip_bf16.h>

// Output: (1, 8, 4096, 4096) float32, 512 MiB per call -> write-BW bound.
//   c in [0,4):  out[c,i,j] = table[seq[i]*4 + c]      (constant along j)
//   c in [4,8):  out[c,i,j] = table[seq[j]*4 + (c-4)]  (same row repeated for all i)
//
// 8192 blocks x 256 threads; each block fills 4 rows (64 KB) of one plane.
// 16 independent 16B stores per thread. R4 change: PLAIN stores, not
// nontemporal — NT stores measured ~3 TB/s vs 6.3 TB/s for plain writeback
// (harness fill kernel) on this device.

#define L 4096

typedef float v4f __attribute__((ext_vector_type(4)));
typedef int   v4i __attribute__((ext_vector_type(4)));

__global__ __launch_bounds__(256) void SequenceEmbedding_30923764532139_kernel(
        const int* __restrict__ seq,
        const float* __restrict__ table,
        float* __restrict__ out) {
    unsigned b = blockIdx.x;
    unsigned t = threadIdx.x;
    unsigned c = b >> 10;            // plane 0..7 (block-uniform)
    unsigned g = b & 1023u;          // row-group: rows 4g .. 4g+3
    unsigned i0 = g << 2;
    unsigned cc = c & 3u;            // table column for this plane

    // table column cc, one value per base id (seq values are 0..3)
    float t0 = table[0u * 4u + cc];
    float t1 = table[1u * 4u + cc];
    float t2 = table[2u * 4u + cc];
    float t3 = table[3u * 4u + cc];

    size_t plane = (size_t)c << 24;  // c * L * L elements
    v4f* outv = (v4f*)out;

    if (c < 4u) {
        // Row value constant along j; 4 rows, 4 chunks each.
        #pragma unroll
        for (int r = 0; r < 4; ++r) {
            unsigned i = i0 + (unsigned)r;
            int s = seq[i];                       // wave-broadcast load
            float x = s == 0 ? t0 : s == 1 ? t1 : s == 2 ? t2 : t3;
            v4f val = {x, x, x, x};
            size_t base = (plane + (size_t)i * L) >> 2;   // v4f index
            #pragma unroll
            for (int k = 0; k < 4; ++k)
                outv[base + t + 256u * (unsigned)k] = val;
        }
    } else {
        // Row content identical for every i: compute the 4 chunks once, store x4 rows.
        v4f vals[4];
        #pragma unroll
        for (int k = 0; k < 4; ++k) {
            unsigned jf4 = t + 256u * (unsigned)k;        // float4 index within row
            v4i s = *(const v4i*)(seq + 4u * jf4);        // coalesced 16B load
            v4f v;
            v.x = s.x == 0 ? t0 : s.x == 1 ? t1 : s.x == 2 ? t2 : t3;
            v.y = s.y == 0 ? t0 : s.y == 1 ? t1 : s.y == 2 ? t2 : t3;
            v.z = s.z == 0 ? t0 : s.z == 1 ? t1 : s.z == 2 ? t2 : t3;
            v.w = s.w == 0 ? t0 : s.w == 1 ? t1 : s.w == 2 ? t2 : t3;
            vals[k] = v;
        }
        #pragma unroll
        for (int r = 0; r < 4; ++r) {
            size_t base = (plane + (size_t)(i0 + (unsigned)r) * L) >> 2;
            #pragma unroll
            for (int k = 0; k < 4; ++k)
                outv[base + t + 256u * (unsigned)k] = vals[k];
        }
    }
}

extern "C" void kernel_launch(void* const* d_in, const int* in_sizes, int n_in,
                              void* d_out, int out_size, void* d_ws, size_t ws_size,
                              hipStream_t stream) {
    const int*   seq   = (const int*)d_in[0];
    const float* table = (const float*)d_in[1];
    float*       out   = (float*)d_out;

    dim3 block(256);
    dim3 grid(8192);   // 8 planes x 1024 row-groups; 64 KB per block
    SequenceEmbedding_30923764532139_kernel<<<grid, block, 0, stream>>>(seq, table, out);
}